// Round 5
// baseline (274.231 us; speedup 1.0000x reference)
//
#include <hip/hip_runtime.h>
#include <stdint.h>

#define NB 8
#define NN 107136
#define TOTAL (NB * NN)
#define NPAIR (NN / 2)       // 53568
#define PRE 2048
#define POST 128
#define CAP 4096
#define HBINS 128            // 16-bit key bins restricted to s in [0.5, 1)
#define KEYBASE 0xBF00u
#define SCORE_TH 0.05f
#define SH_BPB 53            // score/hist blocks per batch (53*1024 >= 53568 pairs)

// ---------------- ws layout (bytes) ----------------
static constexpr size_t OFF_SCORES = 0;
static constexpr size_t SZ_SCORES  = (size_t)TOTAL * 4;
static constexpr size_t OFF_HIST   = OFF_SCORES + SZ_SCORES;       // partial hists
static constexpr size_t SZ_HIST    = (size_t)NB * SH_BPB * HBINS * 4;
static constexpr size_t OFF_CNT    = OFF_HIST + SZ_HIST;           // 8 x 64 u32 (256B apart)
static constexpr size_t SZ_CNT     = (size_t)NB * 64 * 4;
static constexpr size_t OFF_CAND   = OFF_CNT + SZ_CNT + 256;
static constexpr size_t SZ_CAND    = (size_t)NB * CAP * 8;
static constexpr size_t OFF_SELS   = OFF_CAND + SZ_CAND;
static constexpr size_t OFF_SELI   = OFF_SELS + (size_t)NB * PRE * 4;
static constexpr size_t OFF_SELB   = OFF_SELI + (size_t)NB * PRE * 4;
static constexpr size_t OFF_SBB    = OFF_SELB + (size_t)NB * PRE * 7 * 4;
static constexpr size_t OFF_SAR    = OFF_SBB + (size_t)NB * PRE * 4 * 4;
static constexpr size_t OFF_MASK   = OFF_SAR + (size_t)NB * PRE * 4;
static constexpr size_t SZ_MASK    = (size_t)NB * PRE * 32 * 8;

// ---------------- kernels ----------------

// fused softmax scores + per-segment partial 128-bin histogram + zero counts
__global__ void __launch_bounds__(256) k_scoreshist(const float* __restrict__ cls,
                                                    float* __restrict__ scores,
                                                    uint32_t* __restrict__ hp,
                                                    uint32_t* __restrict__ counts) {
    int b = blockIdx.y;
    if (blockIdx.x == 0 && threadIdx.x == 0) counts[(size_t)b * 64] = 0u;
    __shared__ uint32_t lh[HBINS];
    int t = threadIdx.x;
    if (t < HBINS) lh[t] = 0u;
    __syncthreads();
    const float4* cp = (const float4*)cls + (size_t)b * NPAIR;
    float2* sp = (float2*)scores + (size_t)b * NPAIR;
#pragma unroll
    for (int k = 0; k < 4; k++) {
        int p = blockIdx.x * 1024 + k * 256 + t;
        if (p < NPAIR) {
            float4 c = cp[p];
            float m0 = fmaxf(c.x, c.y);
            float s0 = __fdiv_rn(expf(__fsub_rn(c.y, m0)),
                                 __fadd_rn(expf(__fsub_rn(c.x, m0)), expf(__fsub_rn(c.y, m0))));
            float m1 = fmaxf(c.z, c.w);
            float s1 = __fdiv_rn(expf(__fsub_rn(c.w, m1)),
                                 __fadd_rn(expf(__fsub_rn(c.z, m1)), expf(__fsub_rn(c.w, m1))));
            sp[p] = make_float2(s0, s1);
            if (s0 >= 0.5f) {
                uint32_t bin = ((__float_as_uint(s0) >> 16) | 0x8000u) - KEYBASE;
                if (bin > 127u) bin = 127u;
                atomicAdd(&lh[bin], 1u);
            }
            if (s1 >= 0.5f) {
                uint32_t bin = ((__float_as_uint(s1) >> 16) | 0x8000u) - KEYBASE;
                if (bin > 127u) bin = 127u;
                atomicAdd(&lh[bin], 1u);
            }
        }
    }
    __syncthreads();
    if (t < HBINS) hp[((size_t)b * SH_BPB + blockIdx.x) * HBINS + t] = lh[t];
}

// compact with INLINE per-wave threshold-find (sums partial hists, suffix-scan)
__global__ void __launch_bounds__(256) k_compact(const float* __restrict__ scores,
                                                 const uint32_t* __restrict__ hp,
                                                 uint32_t* __restrict__ counts,
                                                 uint64_t* __restrict__ cand) {
    int g2 = blockIdx.x * 256 + threadIdx.x;      // pair index; grid exact
    int lane = threadIdx.x & 63, wid = threadIdx.x >> 6;
    int e0 = 2 * g2;
    int b = e0 / NN;                              // wave-uniform (NN % 128 == 0)

    // ---- wave-redundant findT: each lane sums 2 bins over all segments ----
    uint32_t h0 = 0, h1 = 0;
    const uint32_t* hb = hp + (size_t)b * SH_BPB * HBINS;
#pragma unroll 4
    for (int sg = 0; sg < SH_BPB; sg++) {
        h0 += hb[sg * HBINS + 2 * lane];
        h1 += hb[sg * HBINS + 2 * lane + 1];
    }
    uint32_t v = h0 + h1;
    for (int off = 1; off < 64; off <<= 1) {
        uint32_t u = __shfl_down(v, off);
        if (lane + off >= 64) u = 0u;
        v += u;
    }
    uint32_t total = __shfl(v, 0);
    int c = -1;
    if (v - h0 >= PRE) c = 2 * lane + 1;
    else if (v >= PRE) c = 2 * lane;
    for (int off = 32; off > 0; off >>= 1) c = max(c, __shfl_xor(c, off));
    uint32_t Tb = (total >= PRE && c >= 0) ? (KEYBASE + (uint32_t)c) : 0u;

    // ---- threshold test + block-aggregated slot reservation ----
    float2 sv = ((const float2*)scores)[g2];
    uint32_t key0 = __float_as_uint(sv.x) | 0x80000000u;
    uint32_t key1 = __float_as_uint(sv.y) | 0x80000000u;
    bool p0 = (sv.x >= SCORE_TH) && ((key0 >> 16) >= Tb);
    bool p1 = (sv.y >= SCORE_TH) && ((key1 >> 16) >= Tb);
    uint64_t bal0 = __ballot(p0), bal1 = __ballot(p1);
    uint32_t n0 = (uint32_t)__popcll(bal0);
    uint32_t wcnt = n0 + (uint32_t)__popcll(bal1);
    uint64_t below = (1ull << lane) - 1ull;
    uint32_t off0 = (uint32_t)__popcll(bal0 & below);
    uint32_t off1 = n0 + (uint32_t)__popcll(bal1 & below);
    __shared__ uint32_t lcnt[2];
    __shared__ uint32_t gbase[2];
    __shared__ uint32_t wbase[4];
    int b0 = (blockIdx.x * 512) / NN;
    if (threadIdx.x < 2) lcnt[threadIdx.x] = 0u;
    __syncthreads();
    if (lane == 0 && wcnt) wbase[wid] = atomicAdd(&lcnt[b - b0], wcnt);
    __syncthreads();
    if (threadIdx.x < 2 && lcnt[threadIdx.x])
        gbase[threadIdx.x] = atomicAdd(&counts[(size_t)(b0 + threadIdx.x) * 64], lcnt[threadIdx.x]);
    __syncthreads();
    if (p0 | p1) {
        uint32_t base = gbase[b - b0] + wbase[wid];
        if (p0) {
            uint32_t slot = base + off0;
            if (slot < CAP)
                cand[(size_t)b * CAP + slot] =
                    ((uint64_t)key0 << 32) | (uint64_t)(0xFFFFFFFFu - (uint32_t)(e0 - b * NN));
        }
        if (p1) {
            uint32_t slot = base + off1;
            if (slot < CAP)
                cand[(size_t)b * CAP + slot] =
                    ((uint64_t)key1 << 32) | (uint64_t)(0xFFFFFFFFu - (uint32_t)(e0 + 1 - b * NN));
        }
    }
}

// rank via scalar-pipe j-sweep (uniform address -> s_load; v_cmp_u64 vs SGPR pair),
// then inline decode + scatter to sel[rank]. One thread per candidate.
__global__ void __launch_bounds__(256) k_rank_decode(
        const uint64_t* __restrict__ cand, const uint32_t* __restrict__ counts,
        const float* __restrict__ box_preds, const float* __restrict__ anchors,
        float* __restrict__ selS, uint32_t* __restrict__ selI,
        float* __restrict__ selB, float* __restrict__ selBB, float* __restrict__ selA) {
    int b = blockIdx.y;
    int m = (int)counts[(size_t)b * 64]; if (m > CAP) m = CAP;
    if (blockIdx.x * 256 >= m) return;            // uniform exit
    int i = blockIdx.x * 256 + threadIdx.x;
    const uint64_t* cb = cand + (size_t)b * CAP;
    uint64_t mykey = (i < m) ? cb[i] : ~0ull;
    uint32_t rank = 0;
    int j = 0;
    for (; j + 8 <= m; j += 8) {
#pragma unroll
        for (int u = 0; u < 8; u++) {
            uint64_t jk = cb[j + u];              // wave-uniform -> scalar load
            rank += (jk > mykey) ? 1u : 0u;
        }
    }
    for (; j < m; j++) rank += (cb[j] > mykey) ? 1u : 0u;
    if (i >= m || rank >= PRE) return;

    size_t o = (size_t)b * PRE + rank;
    uint32_t key = (uint32_t)(mykey >> 32);
    uint32_t idx = 0xFFFFFFFFu - (uint32_t)(mykey & 0xFFFFFFFFull);
    float score = __uint_as_float(key & 0x7FFFFFFFu);
    const float* bp = box_preds + ((size_t)b * NN + idx) * 7;
    const float* an = anchors + ((size_t)b * NN + idx) * 7;
    float xa = an[0], ya = an[1], za = an[2], wa = an[3], la = an[4], ha = an[5], ra = an[6];
    float xt = bp[0], yt = bp[1], zt = bp[2], wt = bp[3], lt = bp[4], ht = bp[5], rt = bp[6];
    float za2  = __fadd_rn(za, __fmul_rn(ha, 0.5f));
    float diag = sqrtf(__fadd_rn(__fmul_rn(la, la), __fmul_rn(wa, wa)));
    float xg = __fadd_rn(__fmul_rn(xt, diag), xa);
    float yg = __fadd_rn(__fmul_rn(yt, diag), ya);
    float zg = __fadd_rn(__fmul_rn(zt, ha), za2);
    float lg = __fmul_rn(expf(lt), la);
    float wg = __fmul_rn(expf(wt), wa);
    float hg = __fmul_rn(expf(ht), ha);
    float rg = __fadd_rn(rt, ra);
    zg = __fsub_rn(zg, __fmul_rn(hg, 0.5f));
    selS[o] = score; selI[o] = idx;
    selB[o * 7 + 0] = xg; selB[o * 7 + 1] = yg; selB[o * 7 + 2] = zg;
    selB[o * 7 + 3] = wg; selB[o * 7 + 4] = lg; selB[o * 7 + 5] = hg;
    selB[o * 7 + 6] = rg;
    float cc = fabsf(cosf(rg)), ss = fabsf(sinf(rg));
    float hx = __fmul_rn(0.5f, __fadd_rn(__fmul_rn(wg, cc), __fmul_rn(lg, ss)));
    float hy = __fmul_rn(0.5f, __fadd_rn(__fmul_rn(wg, ss), __fmul_rn(lg, cc)));
    float x1 = __fsub_rn(xg, hx), y1 = __fsub_rn(yg, hy);
    float x2 = __fadd_rn(xg, hx), y2 = __fadd_rn(yg, hy);
    selBB[o * 4 + 0] = x1; selBB[o * 4 + 1] = y1;
    selBB[o * 4 + 2] = x2; selBB[o * 4 + 3] = y2;
    selA[o] = __fmul_rn(__fsub_rn(x2, x1), __fsub_rn(y2, y1));
}

// suppression bitmask rows; div-free exact compare; 32 rows/block (512 blocks)
__global__ void __launch_bounds__(256) k_iou(const float* __restrict__ selBB,
                                             const float* __restrict__ selA,
                                             uint64_t* __restrict__ maskrows) {
    int b = blockIdx.y;
    int r0 = blockIdx.x * 32;
    __shared__ float sx1[PRE], sy1[PRE], sx2[PRE], sy2[PRE], sar[PRE];  // 40 KiB
    int t = threadIdx.x;
    for (int i = t; i < PRE; i += 256) {
        const float* p = selBB + ((size_t)b * PRE + i) * 4;
        sx1[i] = p[0]; sy1[i] = p[1]; sx2[i] = p[2]; sy2[i] = p[3];
        sar[i] = selA[(size_t)b * PRE + i];
    }
    __syncthreads();
    int w  = t & 31;
    int rl = t >> 5;
    int jbase = w * 64;
    float rx1[4], ry1[4], rx2[4], ry2[4], rar[4];
    int rows[4];
#pragma unroll
    for (int p = 0; p < 4; p++) {
        int i = r0 + rl * 4 + p;
        rows[p] = i;
        rx1[p] = sx1[i]; ry1[p] = sy1[i]; rx2[p] = sx2[i]; ry2[p] = sy2[i]; rar[p] = sar[i];
    }
    uint64_t bits[4] = {0, 0, 0, 0};
    for (int jj = 0; jj < 64; jj++) {
        int j = jbase + ((jj + w) & 63);
        float xj1 = sx1[j], yj1 = sy1[j], xj2 = sx2[j], yj2 = sy2[j], aj = sar[j];
#pragma unroll
        for (int p = 0; p < 4; p++) {
            float ix = fmaxf(0.f, __fsub_rn(fminf(rx2[p], xj2), fmaxf(rx1[p], xj1)));
            float iy = fmaxf(0.f, __fsub_rn(fminf(ry2[p], yj2), fmaxf(ry1[p], yj1)));
            float inter = __fmul_rn(ix, iy);
            float den = fmaxf(__fsub_rn(__fadd_rn(rar[p], aj), inter), 1e-8f);
            if (inter > __fmul_rn(0.5f, den) && j > rows[p])
                bits[p] |= (1ull << (j - jbase));
        }
    }
#pragma unroll
    for (int p = 0; p < 4; p++)
        maskrows[((size_t)b * PRE + rows[p]) * 32 + w] = bits[p];
}

// sequential greedy NMS (one wave, depth-8 prefetch) + finalize 128 outputs
__global__ void __launch_bounds__(128) k_nms_final(
        const uint64_t* __restrict__ maskrows, const float* __restrict__ selS,
        const uint32_t* __restrict__ selI, const float* __restrict__ selB,
        const uint32_t* __restrict__ counts, const float* __restrict__ dir_preds,
        float* __restrict__ out) {
    int b = blockIdx.x;
    __shared__ int keptIdx[POST];
    __shared__ int keptCount;
    int t = threadIdx.x;
    int Mv = (int)counts[(size_t)b * 64]; if (Mv > PRE) Mv = PRE;
    if (t < 64) {
        uint64_t removed = 0ull;
        int kc = 0;
        const uint64_t* mb = maskrows + (size_t)b * PRE * 32;
        uint64_t pre[8];
#pragma unroll
        for (int d = 0; d < 8; d++)
            pre[d] = (t < 32 && d < Mv) ? mb[(size_t)d * 32 + t] : 0ull;
        for (int i = 0; i < Mv && kc < POST; i++) {
            uint64_t mrow = pre[i & 7];
            int nf = i + 8;
            pre[i & 7] = (t < 32 && nf < Mv) ? mb[(size_t)nf * 32 + t] : 0ull;
            uint64_t rw = __shfl(removed, i >> 6);
            if (!((rw >> (i & 63)) & 1ull)) {
                if (t == 0) keptIdx[kc] = i;
                kc++;
                removed |= mrow;
            }
        }
        if (t == 0) keptCount = kc;
    }
    __syncthreads();
    int kc = keptCount;
    size_t ob = (size_t)b * POST + t;
    float box[7] = {0.f, 0.f, 0.f, 0.f, 0.f, 0.f, 0.f};
    float sc = 0.f, mk = 0.f;
    if (t < kc) {
        int i = keptIdx[t];
        size_t o = (size_t)b * PRE + i;
        float s = selS[o];
        uint32_t idx = selI[o];
        const float* bx = selB + o * 7;
        float d0 = dir_preds[((size_t)b * NN + idx) * 2 + 0];
        float d1 = dir_preds[((size_t)b * NN + idx) * 2 + 1];
        float label = (d1 > d0) ? 1.0f : 0.0f;
        const float period = 3.14159265358979323846f;
        float r = bx[6];
        float dir_rot = __fsub_rn(r, __fmul_rn(floorf(__fdiv_rn(r, period)), period));
        float nr = __fadd_rn(dir_rot, __fmul_rn(period, label));
        float x = bx[0], y = bx[1], z = bx[2];
        bool in_range = (x >= 0.0f) && (y >= -39.68f) && (z >= -5.0f) &&
                        (x <= 69.12f) && (y <= 39.68f) && (z <= 5.0f);
        if (in_range) {
            box[0] = x; box[1] = y; box[2] = z;
            box[3] = bx[3]; box[4] = bx[4]; box[5] = bx[5]; box[6] = nr;
            sc = s; mk = 1.f;
        }
    }
    float* out_b = out;
    float* out_s = out + 7168;
    float* out_l = out + 8192;
    float* out_m = out + 9216;
    for (int c = 0; c < 7; c++) out_b[ob * 7 + c] = box[c];
    out_s[ob] = sc;
    out_l[ob] = 0.f;
    out_m[ob] = mk;
}

extern "C" void kernel_launch(void* const* d_in, const int* in_sizes, int n_in,
                              void* d_out, int out_size, void* d_ws, size_t ws_size,
                              hipStream_t stream) {
    const float* box_preds = (const float*)d_in[0];
    const float* cls_preds = (const float*)d_in[1];
    const float* dir_preds = (const float*)d_in[2];
    const float* anchors   = (const float*)d_in[3];
    float* out = (float*)d_out;
    char* ws = (char*)d_ws;

    float*    scores = (float*)(ws + OFF_SCORES);
    uint32_t* hp     = (uint32_t*)(ws + OFF_HIST);
    uint32_t* counts = (uint32_t*)(ws + OFF_CNT);
    uint64_t* cand   = (uint64_t*)(ws + OFF_CAND);
    float*    selS   = (float*)(ws + OFF_SELS);
    uint32_t* selI   = (uint32_t*)(ws + OFF_SELI);
    float*    selB   = (float*)(ws + OFF_SELB);
    float*    selBB  = (float*)(ws + OFF_SBB);
    float*    selA   = (float*)(ws + OFF_SAR);
    uint64_t* maskrows = (uint64_t*)(ws + OFF_MASK);

    dim3 gSH(SH_BPB, NB);
    k_scoreshist<<<gSH, 256, 0, stream>>>(cls_preds, scores, hp, counts);
    k_compact<<<TOTAL / 512, 256, 0, stream>>>(scores, hp, counts, cand);
    dim3 gRank(CAP / 256, NB);
    k_rank_decode<<<gRank, 256, 0, stream>>>(cand, counts, box_preds, anchors,
                                             selS, selI, selB, selBB, selA);
    dim3 gIou(PRE / 32, NB);
    k_iou<<<gIou, 256, 0, stream>>>(selBB, selA, maskrows);
    k_nms_final<<<NB, 128, 0, stream>>>(maskrows, selS, selI, selB, counts,
                                        dir_preds, out);
}

// Round 6
// 208.997 us; speedup vs baseline: 1.3121x; 1.3121x over previous
//
#include <hip/hip_runtime.h>
#include <stdint.h>

#define NB 8
#define NN 107136
#define TOTAL (NB * NN)
#define NPAIR (NN / 2)       // 53568
#define PRE 2048
#define POST 128
#define CAP 4096
#define HBINS 128            // 16-bit key bins restricted to s in [0.5, 1)
#define KEYBASE 0xBF00u
#define SCORE_TH 0.05f
#define SH_BPB 53            // score/hist blocks per batch (53*1024 >= 53568 pairs)

// ---------------- ws layout (bytes) ----------------
static constexpr size_t OFF_SCORES = 0;
static constexpr size_t SZ_SCORES  = (size_t)TOTAL * 4;
static constexpr size_t OFF_HIST   = OFF_SCORES + SZ_SCORES;       // partial hists
static constexpr size_t SZ_HIST    = (size_t)NB * SH_BPB * HBINS * 4;
static constexpr size_t OFF_CNT    = OFF_HIST + SZ_HIST;           // 8 x 64 u32 (256B apart)
static constexpr size_t SZ_CNT     = (size_t)NB * 64 * 4;
static constexpr size_t OFF_CAND   = OFF_CNT + SZ_CNT + 256;
static constexpr size_t SZ_CAND    = (size_t)NB * CAP * 8;
static constexpr size_t OFF_SELS   = OFF_CAND + SZ_CAND;
static constexpr size_t OFF_SELI   = OFF_SELS + (size_t)NB * PRE * 4;
static constexpr size_t OFF_SELB   = OFF_SELI + (size_t)NB * PRE * 4;
static constexpr size_t OFF_SBB    = OFF_SELB + (size_t)NB * PRE * 7 * 4;
static constexpr size_t OFF_SAR    = OFF_SBB + (size_t)NB * PRE * 4 * 4;
static constexpr size_t OFF_MASK   = OFF_SAR + (size_t)NB * PRE * 4;
static constexpr size_t SZ_MASK    = (size_t)NB * PRE * 32 * 8;

// ---------------- kernels ----------------

// fused softmax scores + per-segment partial 128-bin histogram + zero counts/cand
__global__ void __launch_bounds__(256) k_scoreshist(const float* __restrict__ cls,
                                                    float* __restrict__ scores,
                                                    uint32_t* __restrict__ hp,
                                                    uint32_t* __restrict__ counts,
                                                    uint64_t* __restrict__ cand) {
    int b = blockIdx.y;
    int t = threadIdx.x;
    if (blockIdx.x == 0 && t == 0) counts[(size_t)b * 64] = 0u;
    if (blockIdx.x < 16)                       // zero-pad cand (rank padding)
        cand[(size_t)b * CAP + blockIdx.x * 256 + t] = 0ull;
    __shared__ uint32_t lh[HBINS];
    if (t < HBINS) lh[t] = 0u;
    __syncthreads();
    const float4* cp = (const float4*)cls + (size_t)b * NPAIR;
    float2* sp = (float2*)scores + (size_t)b * NPAIR;
#pragma unroll
    for (int k = 0; k < 4; k++) {
        int p = blockIdx.x * 1024 + k * 256 + t;
        if (p < NPAIR) {
            float4 c = cp[p];
            float m0 = fmaxf(c.x, c.y);
            float s0 = __fdiv_rn(expf(__fsub_rn(c.y, m0)),
                                 __fadd_rn(expf(__fsub_rn(c.x, m0)), expf(__fsub_rn(c.y, m0))));
            float m1 = fmaxf(c.z, c.w);
            float s1 = __fdiv_rn(expf(__fsub_rn(c.w, m1)),
                                 __fadd_rn(expf(__fsub_rn(c.z, m1)), expf(__fsub_rn(c.w, m1))));
            sp[p] = make_float2(s0, s1);
            if (s0 >= 0.5f) {
                uint32_t bin = ((__float_as_uint(s0) >> 16) | 0x8000u) - KEYBASE;
                if (bin > 127u) bin = 127u;
                atomicAdd(&lh[bin], 1u);
            }
            if (s1 >= 0.5f) {
                uint32_t bin = ((__float_as_uint(s1) >> 16) | 0x8000u) - KEYBASE;
                if (bin > 127u) bin = 127u;
                atomicAdd(&lh[bin], 1u);
            }
        }
    }
    __syncthreads();
    if (t < HBINS) hp[((size_t)b * SH_BPB + blockIdx.x) * HBINS + t] = lh[t];
}

// compact with inline per-wave threshold-find (sums partial hists, suffix-scan)
__global__ void __launch_bounds__(256) k_compact(const float* __restrict__ scores,
                                                 const uint32_t* __restrict__ hp,
                                                 uint32_t* __restrict__ counts,
                                                 uint64_t* __restrict__ cand) {
    int g2 = blockIdx.x * 256 + threadIdx.x;      // pair index; grid exact
    int lane = threadIdx.x & 63, wid = threadIdx.x >> 6;
    int e0 = 2 * g2;
    int b = e0 / NN;                              // wave-uniform (NN % 128 == 0)

    // ---- wave-redundant findT: each lane sums 2 bins over all segments ----
    uint32_t h0 = 0, h1 = 0;
    const uint32_t* hb = hp + (size_t)b * SH_BPB * HBINS;
#pragma unroll 4
    for (int sg = 0; sg < SH_BPB; sg++) {
        h0 += hb[sg * HBINS + 2 * lane];
        h1 += hb[sg * HBINS + 2 * lane + 1];
    }
    uint32_t v = h0 + h1;
    for (int off = 1; off < 64; off <<= 1) {
        uint32_t u = __shfl_down(v, off);
        if (lane + off >= 64) u = 0u;
        v += u;
    }
    uint32_t total = __shfl(v, 0);
    int c = -1;
    if (v - h0 >= PRE) c = 2 * lane + 1;
    else if (v >= PRE) c = 2 * lane;
    for (int off = 32; off > 0; off >>= 1) c = max(c, __shfl_xor(c, off));
    uint32_t Tb = (total >= PRE && c >= 0) ? (KEYBASE + (uint32_t)c) : 0u;

    // ---- threshold test + block-aggregated slot reservation ----
    float2 sv = ((const float2*)scores)[g2];
    uint32_t key0 = __float_as_uint(sv.x) | 0x80000000u;
    uint32_t key1 = __float_as_uint(sv.y) | 0x80000000u;
    bool p0 = (sv.x >= SCORE_TH) && ((key0 >> 16) >= Tb);
    bool p1 = (sv.y >= SCORE_TH) && ((key1 >> 16) >= Tb);
    uint64_t bal0 = __ballot(p0), bal1 = __ballot(p1);
    uint32_t n0 = (uint32_t)__popcll(bal0);
    uint32_t wcnt = n0 + (uint32_t)__popcll(bal1);
    uint64_t below = (1ull << lane) - 1ull;
    uint32_t off0 = (uint32_t)__popcll(bal0 & below);
    uint32_t off1 = n0 + (uint32_t)__popcll(bal1 & below);
    __shared__ uint32_t lcnt[2];
    __shared__ uint32_t gbase[2];
    __shared__ uint32_t wbase[4];
    int b0 = (blockIdx.x * 512) / NN;
    if (threadIdx.x < 2) lcnt[threadIdx.x] = 0u;
    __syncthreads();
    if (lane == 0 && wcnt) wbase[wid] = atomicAdd(&lcnt[b - b0], wcnt);
    __syncthreads();
    if (threadIdx.x < 2 && lcnt[threadIdx.x])
        gbase[threadIdx.x] = atomicAdd(&counts[(size_t)(b0 + threadIdx.x) * 64], lcnt[threadIdx.x]);
    __syncthreads();
    if (p0 | p1) {
        uint32_t base = gbase[b - b0] + wbase[wid];
        if (p0) {
            uint32_t slot = base + off0;
            if (slot < CAP)
                cand[(size_t)b * CAP + slot] =
                    ((uint64_t)key0 << 32) | (uint64_t)(0xFFFFFFFFu - (uint32_t)(e0 - b * NN));
        }
        if (p1) {
            uint32_t slot = base + off1;
            if (slot < CAP)
                cand[(size_t)b * CAP + slot] =
                    ((uint64_t)key1 << 32) | (uint64_t)(0xFFFFFFFFu - (uint32_t)(e0 + 1 - b * NN));
        }
    }
}

// rank via LDS tiles with STATIC 512-iter inner loop (zero-padded cand) + fused decode
__global__ void __launch_bounds__(256) k_rank_decode(
        const uint64_t* __restrict__ cand, const uint32_t* __restrict__ counts,
        const float* __restrict__ box_preds, const float* __restrict__ anchors,
        float* __restrict__ selS, uint32_t* __restrict__ selI,
        float* __restrict__ selB, float* __restrict__ selBB, float* __restrict__ selA) {
    int b = blockIdx.y;
    int m = (int)counts[(size_t)b * 64]; if (m > CAP) m = CAP;
    int i0 = blockIdx.x * 256;
    if (i0 >= m) return;                          // block-uniform exit
    int t = threadIdx.x;
    int i = i0 + t;
    const uint64_t* cb = cand + (size_t)b * CAP;
    uint64_t mykey = (i < m) ? cb[i] : ~0ull;
    __shared__ uint64_t tile[512];
    uint32_t rank = 0;
    int ntiles = (m + 511) >> 9;                  // padded region is zeros: rank-neutral
    for (int tt = 0; tt < ntiles; tt++) {
        int base = tt << 9;
        tile[t] = cb[base + t];
        tile[t + 256] = cb[base + 256 + t];
        __syncthreads();
#pragma unroll 16
        for (int j = 0; j < 512; j++)
            rank += (tile[j] > mykey) ? 1u : 0u;
        __syncthreads();
    }
    if (i >= m || rank >= PRE) return;

    size_t o = (size_t)b * PRE + rank;
    uint32_t key = (uint32_t)(mykey >> 32);
    uint32_t idx = 0xFFFFFFFFu - (uint32_t)(mykey & 0xFFFFFFFFull);
    float score = __uint_as_float(key & 0x7FFFFFFFu);
    const float* bp = box_preds + ((size_t)b * NN + idx) * 7;
    const float* an = anchors + ((size_t)b * NN + idx) * 7;
    float xa = an[0], ya = an[1], za = an[2], wa = an[3], la = an[4], ha = an[5], ra = an[6];
    float xt = bp[0], yt = bp[1], zt = bp[2], wt = bp[3], lt = bp[4], ht = bp[5], rt = bp[6];
    float za2  = __fadd_rn(za, __fmul_rn(ha, 0.5f));
    float diag = sqrtf(__fadd_rn(__fmul_rn(la, la), __fmul_rn(wa, wa)));
    float xg = __fadd_rn(__fmul_rn(xt, diag), xa);
    float yg = __fadd_rn(__fmul_rn(yt, diag), ya);
    float zg = __fadd_rn(__fmul_rn(zt, ha), za2);
    float lg = __fmul_rn(expf(lt), la);
    float wg = __fmul_rn(expf(wt), wa);
    float hg = __fmul_rn(expf(ht), ha);
    float rg = __fadd_rn(rt, ra);
    zg = __fsub_rn(zg, __fmul_rn(hg, 0.5f));
    selS[o] = score; selI[o] = idx;
    selB[o * 7 + 0] = xg; selB[o * 7 + 1] = yg; selB[o * 7 + 2] = zg;
    selB[o * 7 + 3] = wg; selB[o * 7 + 4] = lg; selB[o * 7 + 5] = hg;
    selB[o * 7 + 6] = rg;
    float cc = fabsf(cosf(rg)), ss = fabsf(sinf(rg));
    float hx = __fmul_rn(0.5f, __fadd_rn(__fmul_rn(wg, cc), __fmul_rn(lg, ss)));
    float hy = __fmul_rn(0.5f, __fadd_rn(__fmul_rn(wg, ss), __fmul_rn(lg, cc)));
    float x1 = __fsub_rn(xg, hx), y1 = __fsub_rn(yg, hy);
    float x2 = __fadd_rn(xg, hx), y2 = __fadd_rn(yg, hy);
    selBB[o * 4 + 0] = x1; selBB[o * 4 + 1] = y1;
    selBB[o * 4 + 2] = x2; selBB[o * 4 + 3] = y2;
    selA[o] = __fmul_rn(__fsub_rn(x2, x1), __fsub_rn(y2, y1));
}

// suppression bitmask rows; div-free exact compare; 32 rows/block (512 blocks)
__global__ void __launch_bounds__(256) k_iou(const float* __restrict__ selBB,
                                             const float* __restrict__ selA,
                                             uint64_t* __restrict__ maskrows) {
    int b = blockIdx.y;
    int r0 = blockIdx.x * 32;
    __shared__ float sx1[PRE], sy1[PRE], sx2[PRE], sy2[PRE], sar[PRE];  // 40 KiB
    int t = threadIdx.x;
    for (int i = t; i < PRE; i += 256) {
        const float* p = selBB + ((size_t)b * PRE + i) * 4;
        sx1[i] = p[0]; sy1[i] = p[1]; sx2[i] = p[2]; sy2[i] = p[3];
        sar[i] = selA[(size_t)b * PRE + i];
    }
    __syncthreads();
    int w  = t & 31;
    int rl = t >> 5;
    int jbase = w * 64;
    float rx1[4], ry1[4], rx2[4], ry2[4], rar[4];
    int rows[4];
#pragma unroll
    for (int p = 0; p < 4; p++) {
        int i = r0 + rl * 4 + p;
        rows[p] = i;
        rx1[p] = sx1[i]; ry1[p] = sy1[i]; rx2[p] = sx2[i]; ry2[p] = sy2[i]; rar[p] = sar[i];
    }
    uint64_t bits[4] = {0, 0, 0, 0};
    for (int jj = 0; jj < 64; jj++) {
        int j = jbase + ((jj + w) & 63);
        float xj1 = sx1[j], yj1 = sy1[j], xj2 = sx2[j], yj2 = sy2[j], aj = sar[j];
#pragma unroll
        for (int p = 0; p < 4; p++) {
            float ix = fmaxf(0.f, __fsub_rn(fminf(rx2[p], xj2), fmaxf(rx1[p], xj1)));
            float iy = fmaxf(0.f, __fsub_rn(fminf(ry2[p], yj2), fmaxf(ry1[p], yj1)));
            float inter = __fmul_rn(ix, iy);
            float den = fmaxf(__fsub_rn(__fadd_rn(rar[p], aj), inter), 1e-8f);
            if (inter > __fmul_rn(0.5f, den) && j > rows[p])
                bits[p] |= (1ull << (j - jbase));
        }
    }
#pragma unroll
    for (int p = 0; p < 4; p++)
        maskrows[((size_t)b * PRE + rows[p]) * 32 + w] = bits[p];
}

// sequential greedy NMS (one wave, depth-8 prefetch) + finalize 128 outputs
__global__ void __launch_bounds__(128) k_nms_final(
        const uint64_t* __restrict__ maskrows, const float* __restrict__ selS,
        const uint32_t* __restrict__ selI, const float* __restrict__ selB,
        const uint32_t* __restrict__ counts, const float* __restrict__ dir_preds,
        float* __restrict__ out) {
    int b = blockIdx.x;
    __shared__ int keptIdx[POST];
    __shared__ int keptCount;
    int t = threadIdx.x;
    int Mv = (int)counts[(size_t)b * 64]; if (Mv > PRE) Mv = PRE;
    if (t < 64) {
        uint64_t removed = 0ull;
        int kc = 0;
        const uint64_t* mb = maskrows + (size_t)b * PRE * 32;
        uint64_t pre[8];
#pragma unroll
        for (int d = 0; d < 8; d++)
            pre[d] = (t < 32 && d < Mv) ? mb[(size_t)d * 32 + t] : 0ull;
        for (int i = 0; i < Mv && kc < POST; i++) {
            uint64_t mrow = pre[i & 7];
            int nf = i + 8;
            pre[i & 7] = (t < 32 && nf < Mv) ? mb[(size_t)nf * 32 + t] : 0ull;
            uint64_t rw = __shfl(removed, i >> 6);
            if (!((rw >> (i & 63)) & 1ull)) {
                if (t == 0) keptIdx[kc] = i;
                kc++;
                removed |= mrow;
            }
        }
        if (t == 0) keptCount = kc;
    }
    __syncthreads();
    int kc = keptCount;
    size_t ob = (size_t)b * POST + t;
    float box[7] = {0.f, 0.f, 0.f, 0.f, 0.f, 0.f, 0.f};
    float sc = 0.f, mk = 0.f;
    if (t < kc) {
        int i = keptIdx[t];
        size_t o = (size_t)b * PRE + i;
        float s = selS[o];
        uint32_t idx = selI[o];
        const float* bx = selB + o * 7;
        float d0 = dir_preds[((size_t)b * NN + idx) * 2 + 0];
        float d1 = dir_preds[((size_t)b * NN + idx) * 2 + 1];
        float label = (d1 > d0) ? 1.0f : 0.0f;
        const float period = 3.14159265358979323846f;
        float r = bx[6];
        float dir_rot = __fsub_rn(r, __fmul_rn(floorf(__fdiv_rn(r, period)), period));
        float nr = __fadd_rn(dir_rot, __fmul_rn(period, label));
        float x = bx[0], y = bx[1], z = bx[2];
        bool in_range = (x >= 0.0f) && (y >= -39.68f) && (z >= -5.0f) &&
                        (x <= 69.12f) && (y <= 39.68f) && (z <= 5.0f);
        if (in_range) {
            box[0] = x; box[1] = y; box[2] = z;
            box[3] = bx[3]; box[4] = bx[4]; box[5] = bx[5]; box[6] = nr;
            sc = s; mk = 1.f;
        }
    }
    float* out_b = out;
    float* out_s = out + 7168;
    float* out_l = out + 8192;
    float* out_m = out + 9216;
    for (int c = 0; c < 7; c++) out_b[ob * 7 + c] = box[c];
    out_s[ob] = sc;
    out_l[ob] = 0.f;
    out_m[ob] = mk;
}

extern "C" void kernel_launch(void* const* d_in, const int* in_sizes, int n_in,
                              void* d_out, int out_size, void* d_ws, size_t ws_size,
                              hipStream_t stream) {
    const float* box_preds = (const float*)d_in[0];
    const float* cls_preds = (const float*)d_in[1];
    const float* dir_preds = (const float*)d_in[2];
    const float* anchors   = (const float*)d_in[3];
    float* out = (float*)d_out;
    char* ws = (char*)d_ws;

    float*    scores = (float*)(ws + OFF_SCORES);
    uint32_t* hp     = (uint32_t*)(ws + OFF_HIST);
    uint32_t* counts = (uint32_t*)(ws + OFF_CNT);
    uint64_t* cand   = (uint64_t*)(ws + OFF_CAND);
    float*    selS   = (float*)(ws + OFF_SELS);
    uint32_t* selI   = (uint32_t*)(ws + OFF_SELI);
    float*    selB   = (float*)(ws + OFF_SELB);
    float*    selBB  = (float*)(ws + OFF_SBB);
    float*    selA   = (float*)(ws + OFF_SAR);
    uint64_t* maskrows = (uint64_t*)(ws + OFF_MASK);

    dim3 gSH(SH_BPB, NB);
    k_scoreshist<<<gSH, 256, 0, stream>>>(cls_preds, scores, hp, counts, cand);
    k_compact<<<TOTAL / 512, 256, 0, stream>>>(scores, hp, counts, cand);
    dim3 gRank(CAP / 256, NB);
    k_rank_decode<<<gRank, 256, 0, stream>>>(cand, counts, box_preds, anchors,
                                             selS, selI, selB, selBB, selA);
    dim3 gIou(PRE / 32, NB);
    k_iou<<<gIou, 256, 0, stream>>>(selBB, selA, maskrows);
    k_nms_final<<<NB, 128, 0, stream>>>(maskrows, selS, selI, selB, counts,
                                        dir_preds, out);
}

// Round 7
// 178.037 us; speedup vs baseline: 1.5403x; 1.1739x over previous
//
#include <hip/hip_runtime.h>
#include <stdint.h>

#define NB 8
#define NN 107136
#define TOTAL (NB * NN)
#define NPAIR (NN / 2)       // 53568
#define PRE 2048
#define POST 128
#define CAP 4096
#define HBINS 128            // 16-bit key bins restricted to s in [0.5, 1)
#define KEYBASE 0xBF00u
#define SCORE_TH 0.05f
#define SH_BPB 53            // score/hist blocks per batch (53*1024 >= 53568 pairs)

// ---------------- ws layout (bytes) ----------------
static constexpr size_t OFF_SCORES = 0;
static constexpr size_t SZ_SCORES  = (size_t)TOTAL * 4;
static constexpr size_t OFF_HIST   = OFF_SCORES + SZ_SCORES;       // partial hists
static constexpr size_t SZ_HIST    = (size_t)NB * SH_BPB * HBINS * 4;
static constexpr size_t OFF_CNT    = OFF_HIST + SZ_HIST;           // 8 x 64 u32 (256B apart)
static constexpr size_t SZ_CNT     = (size_t)NB * 64 * 4;
static constexpr size_t OFF_CAND   = OFF_CNT + SZ_CNT + 256;
static constexpr size_t SZ_CAND    = (size_t)NB * CAP * 8;
static constexpr size_t OFF_SELS   = OFF_CAND + SZ_CAND;
static constexpr size_t OFF_SELI   = OFF_SELS + (size_t)NB * PRE * 4;
static constexpr size_t OFF_SELB   = OFF_SELI + (size_t)NB * PRE * 4;
static constexpr size_t OFF_SBB    = OFF_SELB + (size_t)NB * PRE * 7 * 4;
static constexpr size_t OFF_SAR    = OFF_SBB + (size_t)NB * PRE * 4 * 4;

// ---------------- kernels ----------------

// fused softmax scores + per-segment partial 128-bin histogram + zero counts/cand
__global__ void __launch_bounds__(256) k_scoreshist(const float* __restrict__ cls,
                                                    float* __restrict__ scores,
                                                    uint32_t* __restrict__ hp,
                                                    uint32_t* __restrict__ counts,
                                                    uint64_t* __restrict__ cand) {
    int b = blockIdx.y;
    int t = threadIdx.x;
    if (blockIdx.x == 0 && t == 0) counts[(size_t)b * 64] = 0u;
    if (blockIdx.x < 16)                       // zero-pad cand (rank padding)
        cand[(size_t)b * CAP + blockIdx.x * 256 + t] = 0ull;
    __shared__ uint32_t lh[HBINS];
    if (t < HBINS) lh[t] = 0u;
    __syncthreads();
    const float4* cp = (const float4*)cls + (size_t)b * NPAIR;
    float2* sp = (float2*)scores + (size_t)b * NPAIR;
#pragma unroll
    for (int k = 0; k < 4; k++) {
        int p = blockIdx.x * 1024 + k * 256 + t;
        if (p < NPAIR) {
            float4 c = cp[p];
            float m0 = fmaxf(c.x, c.y);
            float s0 = __fdiv_rn(expf(__fsub_rn(c.y, m0)),
                                 __fadd_rn(expf(__fsub_rn(c.x, m0)), expf(__fsub_rn(c.y, m0))));
            float m1 = fmaxf(c.z, c.w);
            float s1 = __fdiv_rn(expf(__fsub_rn(c.w, m1)),
                                 __fadd_rn(expf(__fsub_rn(c.z, m1)), expf(__fsub_rn(c.w, m1))));
            sp[p] = make_float2(s0, s1);
            if (s0 >= 0.5f) {
                uint32_t bin = ((__float_as_uint(s0) >> 16) | 0x8000u) - KEYBASE;
                if (bin > 127u) bin = 127u;
                atomicAdd(&lh[bin], 1u);
            }
            if (s1 >= 0.5f) {
                uint32_t bin = ((__float_as_uint(s1) >> 16) | 0x8000u) - KEYBASE;
                if (bin > 127u) bin = 127u;
                atomicAdd(&lh[bin], 1u);
            }
        }
    }
    __syncthreads();
    if (t < HBINS) hp[((size_t)b * SH_BPB + blockIdx.x) * HBINS + t] = lh[t];
}

// compact with inline per-wave threshold-find (sums partial hists, suffix-scan)
__global__ void __launch_bounds__(256) k_compact(const float* __restrict__ scores,
                                                 const uint32_t* __restrict__ hp,
                                                 uint32_t* __restrict__ counts,
                                                 uint64_t* __restrict__ cand) {
    int g2 = blockIdx.x * 256 + threadIdx.x;      // pair index; grid exact
    int lane = threadIdx.x & 63, wid = threadIdx.x >> 6;
    int e0 = 2 * g2;
    int b = e0 / NN;                              // wave-uniform (NN % 128 == 0)

    // ---- wave-redundant findT: each lane sums 2 bins over all segments ----
    uint32_t h0 = 0, h1 = 0;
    const uint32_t* hb = hp + (size_t)b * SH_BPB * HBINS;
#pragma unroll 4
    for (int sg = 0; sg < SH_BPB; sg++) {
        h0 += hb[sg * HBINS + 2 * lane];
        h1 += hb[sg * HBINS + 2 * lane + 1];
    }
    uint32_t v = h0 + h1;
    for (int off = 1; off < 64; off <<= 1) {
        uint32_t u = __shfl_down(v, off);
        if (lane + off >= 64) u = 0u;
        v += u;
    }
    uint32_t total = __shfl(v, 0);
    int c = -1;
    if (v - h0 >= PRE) c = 2 * lane + 1;
    else if (v >= PRE) c = 2 * lane;
    for (int off = 32; off > 0; off >>= 1) c = max(c, __shfl_xor(c, off));
    uint32_t Tb = (total >= PRE && c >= 0) ? (KEYBASE + (uint32_t)c) : 0u;

    // ---- threshold test + block-aggregated slot reservation ----
    float2 sv = ((const float2*)scores)[g2];
    uint32_t key0 = __float_as_uint(sv.x) | 0x80000000u;
    uint32_t key1 = __float_as_uint(sv.y) | 0x80000000u;
    bool p0 = (sv.x >= SCORE_TH) && ((key0 >> 16) >= Tb);
    bool p1 = (sv.y >= SCORE_TH) && ((key1 >> 16) >= Tb);
    uint64_t bal0 = __ballot(p0), bal1 = __ballot(p1);
    uint32_t n0 = (uint32_t)__popcll(bal0);
    uint32_t wcnt = n0 + (uint32_t)__popcll(bal1);
    uint64_t below = (1ull << lane) - 1ull;
    uint32_t off0 = (uint32_t)__popcll(bal0 & below);
    uint32_t off1 = n0 + (uint32_t)__popcll(bal1 & below);
    __shared__ uint32_t lcnt[2];
    __shared__ uint32_t gbase[2];
    __shared__ uint32_t wbase[4];
    int b0 = (blockIdx.x * 512) / NN;
    if (threadIdx.x < 2) lcnt[threadIdx.x] = 0u;
    __syncthreads();
    if (lane == 0 && wcnt) wbase[wid] = atomicAdd(&lcnt[b - b0], wcnt);
    __syncthreads();
    if (threadIdx.x < 2 && lcnt[threadIdx.x])
        gbase[threadIdx.x] = atomicAdd(&counts[(size_t)(b0 + threadIdx.x) * 64], lcnt[threadIdx.x]);
    __syncthreads();
    if (p0 | p1) {
        uint32_t base = gbase[b - b0] + wbase[wid];
        if (p0) {
            uint32_t slot = base + off0;
            if (slot < CAP)
                cand[(size_t)b * CAP + slot] =
                    ((uint64_t)key0 << 32) | (uint64_t)(0xFFFFFFFFu - (uint32_t)(e0 - b * NN));
        }
        if (p1) {
            uint32_t slot = base + off1;
            if (slot < CAP)
                cand[(size_t)b * CAP + slot] =
                    ((uint64_t)key1 << 32) | (uint64_t)(0xFFFFFFFFu - (uint32_t)(e0 + 1 - b * NN));
        }
    }
}

// rank via LDS tiles with static 512-iter inner loop (zero-padded cand) + fused decode
__global__ void __launch_bounds__(256) k_rank_decode(
        const uint64_t* __restrict__ cand, const uint32_t* __restrict__ counts,
        const float* __restrict__ box_preds, const float* __restrict__ anchors,
        float* __restrict__ selS, uint32_t* __restrict__ selI,
        float* __restrict__ selB, float* __restrict__ selBB, float* __restrict__ selA) {
    int b = blockIdx.y;
    int m = (int)counts[(size_t)b * 64]; if (m > CAP) m = CAP;
    int i0 = blockIdx.x * 256;
    if (i0 >= m) return;                          // block-uniform exit
    int t = threadIdx.x;
    int i = i0 + t;
    const uint64_t* cb = cand + (size_t)b * CAP;
    uint64_t mykey = (i < m) ? cb[i] : ~0ull;
    __shared__ uint64_t tile[512];
    uint32_t rank = 0;
    int ntiles = (m + 511) >> 9;                  // padded region is zeros: rank-neutral
    for (int tt = 0; tt < ntiles; tt++) {
        int base = tt << 9;
        tile[t] = cb[base + t];
        tile[t + 256] = cb[base + 256 + t];
        __syncthreads();
#pragma unroll 16
        for (int j = 0; j < 512; j++)
            rank += (tile[j] > mykey) ? 1u : 0u;
        __syncthreads();
    }
    if (i >= m || rank >= PRE) return;

    size_t o = (size_t)b * PRE + rank;
    uint32_t key = (uint32_t)(mykey >> 32);
    uint32_t idx = 0xFFFFFFFFu - (uint32_t)(mykey & 0xFFFFFFFFull);
    float score = __uint_as_float(key & 0x7FFFFFFFu);
    const float* bp = box_preds + ((size_t)b * NN + idx) * 7;
    const float* an = anchors + ((size_t)b * NN + idx) * 7;
    float xa = an[0], ya = an[1], za = an[2], wa = an[3], la = an[4], ha = an[5], ra = an[6];
    float xt = bp[0], yt = bp[1], zt = bp[2], wt = bp[3], lt = bp[4], ht = bp[5], rt = bp[6];
    float za2  = __fadd_rn(za, __fmul_rn(ha, 0.5f));
    float diag = sqrtf(__fadd_rn(__fmul_rn(la, la), __fmul_rn(wa, wa)));
    float xg = __fadd_rn(__fmul_rn(xt, diag), xa);
    float yg = __fadd_rn(__fmul_rn(yt, diag), ya);
    float zg = __fadd_rn(__fmul_rn(zt, ha), za2);
    float lg = __fmul_rn(expf(lt), la);
    float wg = __fmul_rn(expf(wt), wa);
    float hg = __fmul_rn(expf(ht), ha);
    float rg = __fadd_rn(rt, ra);
    zg = __fsub_rn(zg, __fmul_rn(hg, 0.5f));
    selS[o] = score; selI[o] = idx;
    selB[o * 7 + 0] = xg; selB[o * 7 + 1] = yg; selB[o * 7 + 2] = zg;
    selB[o * 7 + 3] = wg; selB[o * 7 + 4] = lg; selB[o * 7 + 5] = hg;
    selB[o * 7 + 6] = rg;
    float cc = fabsf(cosf(rg)), ss = fabsf(sinf(rg));
    float hx = __fmul_rn(0.5f, __fadd_rn(__fmul_rn(wg, cc), __fmul_rn(lg, ss)));
    float hy = __fmul_rn(0.5f, __fadd_rn(__fmul_rn(wg, ss), __fmul_rn(lg, cc)));
    float x1 = __fsub_rn(xg, hx), y1 = __fsub_rn(yg, hy);
    float x2 = __fadd_rn(xg, hx), y2 = __fadd_rn(yg, hy);
    selBB[o * 4 + 0] = x1; selBB[o * 4 + 1] = y1;
    selBB[o * 4 + 2] = x2; selBB[o * 4 + 3] = y2;
    selA[o] = __fmul_rn(__fsub_rn(x2, x1), __fsub_rn(y2, y1));
}

// fused greedy NMS (kept list in lane registers, candidates in LDS) + finalize.
// One block per batch; wave 0 scans, all 128 threads stage/finalize.
__global__ void __launch_bounds__(128) k_nms(
        const float* __restrict__ selBB, const float* __restrict__ selA,
        const float* __restrict__ selS, const uint32_t* __restrict__ selI,
        const float* __restrict__ selB, const uint32_t* __restrict__ counts,
        const float* __restrict__ dir_preds, float* __restrict__ out) {
    int b = blockIdx.x;
    int t = threadIdx.x;
    __shared__ float4 sbb[PRE];        // 32 KiB
    __shared__ float  sar[PRE];        // 8 KiB
    __shared__ int keptIdx[POST];
    __shared__ int keptCountSh;
    int Mv = (int)counts[(size_t)b * 64]; if (Mv > PRE) Mv = PRE;
    const float4* bb4 = (const float4*)selBB + (size_t)b * PRE;
    const float*  ar  = selA + (size_t)b * PRE;
    for (int i = t; i < PRE; i += 128) {   // rows >= Mv are poison but never read
        sbb[i] = bb4[i];
        sar[i] = ar[i];
    }
    __syncthreads();
    if (t < 64) {
        int lane = t;
        // kept slots: lane holds slot 'lane' (A) and slot 64+lane (B)
        float ax1 = 1e30f, ay1 = 1e30f, ax2 = 1e30f, ay2 = 1e30f, aar = 0.f;
        float bx1 = 1e30f, by1 = 1e30f, bx2 = 1e30f, by2 = 1e30f, bar = 0.f;
        int kc = 0;
        for (int i = 0; i < Mv && kc < POST; i++) {
            float4 c = sbb[i];             // broadcast ds_read_b128
            float ca = sar[i];
            float ix = fmaxf(0.f, __fsub_rn(fminf(ax2, c.z), fmaxf(ax1, c.x)));
            float iy = fmaxf(0.f, __fsub_rn(fminf(ay2, c.w), fmaxf(ay1, c.y)));
            float inter = __fmul_rn(ix, iy);
            float den = fmaxf(__fsub_rn(__fadd_rn(aar, ca), inter), 1e-8f);
            bool sup = inter > __fmul_rn(0.5f, den);
            ix = fmaxf(0.f, __fsub_rn(fminf(bx2, c.z), fmaxf(bx1, c.x)));
            iy = fmaxf(0.f, __fsub_rn(fminf(by2, c.w), fmaxf(by1, c.y)));
            inter = __fmul_rn(ix, iy);
            den = fmaxf(__fsub_rn(__fadd_rn(bar, ca), inter), 1e-8f);
            sup = sup || (inter > __fmul_rn(0.5f, den));
            if (__ballot(sup) == 0ull) {
                if (lane == 0) keptIdx[kc] = i;
                if (kc < 64) {
                    if (lane == kc) { ax1 = c.x; ay1 = c.y; ax2 = c.z; ay2 = c.w; aar = ca; }
                } else {
                    if (lane == kc - 64) { bx1 = c.x; by1 = c.y; bx2 = c.z; by2 = c.w; bar = ca; }
                }
                kc++;
            }
        }
        if (lane == 0) keptCountSh = kc;
    }
    __syncthreads();
    int kc = keptCountSh;
    size_t ob = (size_t)b * POST + t;
    float box[7] = {0.f, 0.f, 0.f, 0.f, 0.f, 0.f, 0.f};
    float sc = 0.f, mk = 0.f;
    if (t < kc) {
        int i = keptIdx[t];
        size_t o = (size_t)b * PRE + i;
        float s = selS[o];
        uint32_t idx = selI[o];
        const float* bx = selB + o * 7;
        float d0 = dir_preds[((size_t)b * NN + idx) * 2 + 0];
        float d1 = dir_preds[((size_t)b * NN + idx) * 2 + 1];
        float label = (d1 > d0) ? 1.0f : 0.0f;
        const float period = 3.14159265358979323846f;
        float r = bx[6];
        float dir_rot = __fsub_rn(r, __fmul_rn(floorf(__fdiv_rn(r, period)), period));
        float nr = __fadd_rn(dir_rot, __fmul_rn(period, label));
        float x = bx[0], y = bx[1], z = bx[2];
        bool in_range = (x >= 0.0f) && (y >= -39.68f) && (z >= -5.0f) &&
                        (x <= 69.12f) && (y <= 39.68f) && (z <= 5.0f);
        if (in_range) {
            box[0] = x; box[1] = y; box[2] = z;
            box[3] = bx[3]; box[4] = bx[4]; box[5] = bx[5]; box[6] = nr;
            sc = s; mk = 1.f;
        }
    }
    float* out_b = out;
    float* out_s = out + 7168;
    float* out_l = out + 8192;
    float* out_m = out + 9216;
    for (int c = 0; c < 7; c++) out_b[ob * 7 + c] = box[c];
    out_s[ob] = sc;
    out_l[ob] = 0.f;
    out_m[ob] = mk;
}

extern "C" void kernel_launch(void* const* d_in, const int* in_sizes, int n_in,
                              void* d_out, int out_size, void* d_ws, size_t ws_size,
                              hipStream_t stream) {
    const float* box_preds = (const float*)d_in[0];
    const float* cls_preds = (const float*)d_in[1];
    const float* dir_preds = (const float*)d_in[2];
    const float* anchors   = (const float*)d_in[3];
    float* out = (float*)d_out;
    char* ws = (char*)d_ws;

    float*    scores = (float*)(ws + OFF_SCORES);
    uint32_t* hp     = (uint32_t*)(ws + OFF_HIST);
    uint32_t* counts = (uint32_t*)(ws + OFF_CNT);
    uint64_t* cand   = (uint64_t*)(ws + OFF_CAND);
    float*    selS   = (float*)(ws + OFF_SELS);
    uint32_t* selI   = (uint32_t*)(ws + OFF_SELI);
    float*    selB   = (float*)(ws + OFF_SELB);
    float*    selBB  = (float*)(ws + OFF_SBB);
    float*    selA   = (float*)(ws + OFF_SAR);

    dim3 gSH(SH_BPB, NB);
    k_scoreshist<<<gSH, 256, 0, stream>>>(cls_preds, scores, hp, counts, cand);
    k_compact<<<TOTAL / 512, 256, 0, stream>>>(scores, hp, counts, cand);
    dim3 gRank(CAP / 256, NB);
    k_rank_decode<<<gRank, 256, 0, stream>>>(cand, counts, box_preds, anchors,
                                             selS, selI, selB, selBB, selA);
    k_nms<<<NB, 128, 0, stream>>>(selBB, selA, selS, selI, selB, counts,
                                  dir_preds, out);
}